// Round 7
// baseline (192.655 us; speedup 1.0000x reference)
//
#include <hip/hip_runtime.h>

typedef _Float16 f16;
typedef __attribute__((ext_vector_type(8))) _Float16 f16x8;
typedef __attribute__((ext_vector_type(4))) float f32x4;
typedef unsigned int u32;

#define S_      4
#define NPER    12500
#define NF      1024
#define HID     256
#define NSTRUCT 500
#define TM      64

#define GLB __attribute__((address_space(1)))
#define AS3 __attribute__((address_space(3)))

#define WAIT_VM(N)  asm volatile("s_waitcnt vmcnt(" #N ")" ::: "memory")
#define WAIT_LGKM() asm volatile("s_waitcnt lgkmcnt(0)" ::: "memory")
#define SCHED0()    __builtin_amdgcn_sched_barrier(0)
#define BARRIER()   do { __builtin_amdgcn_s_barrier(); SCHED0(); } while (0)

// ---------------------------------------------------------------------------
// Fused weight transpose + fp32->fp16 (all 3 layers, 1 launch)
// ---------------------------------------------------------------------------
__global__ __launch_bounds__(256) void transpose_all_kernel(
    const float* __restrict__ W1, const float* __restrict__ W2,
    const float* __restrict__ W3,
    f16* __restrict__ w1t, f16* __restrict__ w2t, f16* __restrict__ w3t)
{
  const int z = blockIdx.z;            // layer*4 + species
  const int layer = z >> 2, sp = z & 3;
  const float* in; f16* out; int K;
  if (layer == 0)      { in = W1; out = w1t; K = NF;  }
  else if (layer == 1) { in = W2; out = w2t; K = HID; }
  else                 { in = W3; out = w3t; K = HID; }
  if (blockIdx.x * 64 >= K) return;

  __shared__ float tile[64][65];
  const float* inp = in + (size_t)sp * K * HID;
  f16* outp = out + (size_t)sp * K * HID;
  const int k0 = blockIdx.x * 64;
  const int n0 = blockIdx.y * 64;
  const int t = threadIdx.x;
  {
    const int lk = t >> 2;
    const int nq = (t & 3) * 16;
    const float* src = inp + (size_t)(k0 + lk) * HID + n0 + nq;
    #pragma unroll
    for (int i = 0; i < 4; ++i) {
      float4 v = *(const float4*)(src + i * 4);
      tile[lk][nq + i * 4 + 0] = v.x;
      tile[lk][nq + i * 4 + 1] = v.y;
      tile[lk][nq + i * 4 + 2] = v.z;
      tile[lk][nq + i * 4 + 3] = v.w;
    }
  }
  __syncthreads();
  {
    const int ln = t >> 2;
    const int kq = (t & 3) * 16;
    f16* dst = outp + (size_t)(n0 + ln) * K + k0 + kq;
    f16x8 a, b;
    #pragma unroll
    for (int j = 0; j < 8; ++j) a[j] = (f16)tile[kq + j][ln];
    #pragma unroll
    for (int j = 0; j < 8; ++j) b[j] = (f16)tile[kq + 8 + j][ln];
    *(f16x8*)dst = a;
    *(f16x8*)(dst + 8) = b;
  }
}

// ---------------------------------------------------------------------------
// Fused MLP R14 = R13 pipeline mechanics at 48 KB LDS (3 blocks/CU):
//  - KEY INSIGHT: bS is wave-private on BOTH sides (wave w stages and reads
//    only bytes [w*8K,(w+1)*8K)). So it needs NO cross-wave double buffer:
//    single 32 KB bS; per phase, after the MFMA's ds_reads retire
//    (WAIT_LGKM), each wave gll-stages W1(c+1) into its OWN slice.
//  - Arena 48 KB = aS dbuf 2x8K + bS 32K -> 3 blocks/CU (144 KB), grid
//    784/768 = 1.02 resident rounds (was 1.53 at 2 blocks/CU).
//  - Phase order: VMwait -> mfma(c) -> lgkm -> gll W1(c+1) -> stage_feat(c+1)
//    -> pa(c+4) -> lgkm -> barrier.  In-order vmcnt: steady queue at the wait
//    is [pa(c+2), gll(c), pa(c+3)] -> VM(4) drains gll(c), keeps pa(c+3);
//    pa retains ~2-phase HBM cover.  gll's shortened cover (~barrier+stage)
//    is absorbed by the 3rd resident block.
//  - Hidden: single 16 KB wS (also wave-private), stage c+1 after chunk c's
//    reads retire; barrier-free inside layers.
//  - launch_bounds(256,3) caps VGPR at 170 for 12 waves/CU.
// ---------------------------------------------------------------------------

__device__ __forceinline__ void zero_acc(f32x4 (&acc)[4][4]) {
  #pragma unroll
  for (int a = 0; a < 4; ++a)
    #pragma unroll
    for (int b = 0; b < 4; ++b)
      #pragma unroll
      for (int j = 0; j < 4; ++j) acc[a][b][j] = 0.f;
}

// L1 weights: bS [256 n][8 slots of 16B]; phys slot p at row r holds k-slot
// p^(r&7). Wave w stages rows w*64..+63 -- the rows it alone reads.
__device__ __forceinline__ void stage_w64(char* bS, const char* wbase, int c,
                                          int w, int lane)
{
  #pragma unroll
  for (int i = 0; i < 8; ++i) {
    const int seg  = w * 8 + i;                 // 0..31
    const int rloc = lane >> 3;                 // 0..7
    const int p    = lane & 7;                  // phys 16B slot
    const int row  = seg * 8 + rloc;            // 0..255
    const int slog = p ^ rloc;                  // logical k-slot (row&7 == rloc)
    const char* gp = wbase + (size_t)row * (NF * 2) + (size_t)c * 128 + slog * 16;
    char* lp = bS + seg * 1024;                 // wave-uniform base
    __builtin_amdgcn_global_load_lds((const GLB u32*)gp, (AS3 u32*)lp, 16, 0, 0);
  }
}

// Hidden weights: [256 n][32 k], phys slot = log ^ ((row>>1)&3). Self-staged.
__device__ __forceinline__ void stage_w32(char* wS, const char* wbase, int c,
                                          int w, int lane)
{
  #pragma unroll
  for (int i = 0; i < 4; ++i) {
    const int seg = w * 4 + i;                  // 0..15
    const int row = seg * 16 + (lane >> 2);     // 0..255
    const int kbp = lane & 3;
    const int kb  = kbp ^ ((row >> 1) & 3);
    const char* gp = wbase + (size_t)row * (HID * 2) + c * 64 + kb * 16;
    char* lp = wS + seg * 1024;
    __builtin_amdgcn_global_load_lds((const GLB u32*)gp, (AS3 u32*)lp, 16, 0, 0);
  }
}

__device__ __forceinline__ void load_pa(float4 (&pa)[4], const float* fsrcT, int c)
{
  #pragma unroll
  for (int j = 0; j < 4; ++j)
    pa[j] = *(const float4*)(fsrcT + c * 64 + j * 4);
}

// Features chunk [64 r][64 k] fp32->fp16 into aS (ds_write).
__device__ __forceinline__ void stage_feat64(char* aS, const float4 (&pa)[4], int t)
{
  const int r = t >> 2;
  #pragma unroll
  for (int wr = 0; wr < 2; ++wr) {
    f16x8 hv;
    const float4 lo = pa[wr * 2 + 0], hi = pa[wr * 2 + 1];
    hv[0]=(f16)lo.x; hv[1]=(f16)lo.y; hv[2]=(f16)lo.z; hv[3]=(f16)lo.w;
    hv[4]=(f16)hi.x; hv[5]=(f16)hi.y; hv[6]=(f16)hi.z; hv[7]=(f16)hi.w;
    const int slog = (t & 3) * 2 + wr;
    const int p = slog ^ (r & 7);
    *(f16x8*)(aS + r * 128 + p * 16) = hv;
  }
}

// L1 compute: one KC=64 chunk, 32 MFMA.
__device__ __forceinline__ void mfma64_a(f32x4 (&acc)[4][4], const char* aS,
                                         const char* bS, int w, int g, int l15)
{
  #pragma unroll
  for (int ks = 0; ks < 2; ++ks) {
    f16x8 af[4], bf[4];
    #pragma unroll
    for (int at = 0; at < 4; ++at) {
      const int rr = at * 16 + l15;
      const int p  = (ks * 4 + g) ^ (rr & 7);
      af[at] = *(const f16x8*)(aS + rr * 128 + p * 16);
    }
    #pragma unroll
    for (int bt = 0; bt < 4; ++bt) {
      const int nn = w * 64 + bt * 16 + l15;
      const int p  = (ks * 4 + g) ^ (nn & 7);
      bf[bt] = *(const f16x8*)(bS + nn * 128 + p * 16);
    }
    #pragma unroll
    for (int at = 0; at < 4; ++at)
      #pragma unroll
      for (int bt = 0; bt < 4; ++bt)
        acc[at][bt] = __builtin_amdgcn_mfma_f32_16x16x32_f16(af[at], bf[bt], acc[at][bt], 0, 0, 0);
  }
}

// Hidden compute: one KC=32 chunk, 16 MFMA.
__device__ __forceinline__ void mfma32_h(f32x4 (&acc)[4][4], const char* hL, int c,
                                         const char* wS, int w, int g, int l15)
{
  f16x8 af[4], bf[4];
  #pragma unroll
  for (int at = 0; at < 4; ++at) {
    const int rr = at * 16 + l15;
    af[at] = *(const f16x8*)(hL + ((rr * 512 + c * 64 + g * 16) ^ ((rr & 7) << 4)));
  }
  #pragma unroll
  for (int bt = 0; bt < 4; ++bt) {
    const int nn = w * 64 + bt * 16 + l15;
    bf[bt] = *(const f16x8*)(wS + nn * 64 + ((g ^ ((nn >> 1) & 3)) * 16));
  }
  #pragma unroll
  for (int at = 0; at < 4; ++at)
    #pragma unroll
    for (int bt = 0; bt < 4; ++bt)
      acc[at][bt] = __builtin_amdgcn_mfma_f32_16x16x32_f16(af[at], bf[bt], acc[at][bt], 0, 0, 0);
}

__device__ __forceinline__ void silu_store(f32x4 (&acc)[4][4],
                                           const float* __restrict__ bias,
                                           char* hL, int w, int lane)
{
  const int g = lane >> 4, l15 = lane & 15;
  #pragma unroll
  for (int bt = 0; bt < 4; ++bt) {
    const int col = w * 64 + bt * 16 + l15;
    const float b = bias[col];
    #pragma unroll
    for (int at = 0; at < 4; ++at) {
      #pragma unroll
      for (int j = 0; j < 4; ++j) {
        const int row = at * 16 + g * 4 + j;   // m89-verified C/D mapping
        float x = acc[at][bt][j] + b;
        x = x * __builtin_amdgcn_rcpf(1.f + __expf(-x));
        *(f16*)(hL + (((row * HID + col) * 2) ^ ((row & 7) << 4))) = (f16)x;
      }
    }
  }
}

// L1 phase, single-bS: VMwait readies own gll(c); compute; lgkm retires the
// ds_reads (WAR gate for own-slice overwrite); gll W1(c+1) into own slice;
// stage feat(c+1); refill pa(c+4); drain ds_writes; barrier (A publish).
#define L1_STEP(c, ASc, ASn, PAset, VMN, DOG, DOPA)              \
  do {                                                           \
    WAIT_VM(VMN); SCHED0();                                      \
    mfma64_a(acc, ASc, bS, w, g, l15);                           \
    WAIT_LGKM(); SCHED0();                                       \
    if (DOG)  stage_w64(bS, w1s, (c) + 1, w, lane);              \
    stage_feat64(ASn, PAset, t);                                 \
    if (DOPA) load_pa(PAset, fsrcT, (c) + 4);                    \
    WAIT_LGKM(); BARRIER();                                      \
  } while (0)

// Hidden step, single-wS (wave-private): full own-gll drain, compute,
// retire reads, stage next chunk into own slice. Barrier-free.
#define HID_ST(c, wsrc, cs, DOG)                                 \
  do {                                                           \
    WAIT_VM(0); SCHED0();                                        \
    mfma32_h(acc, hL, c, wS, w, g, l15);                         \
    WAIT_LGKM(); SCHED0();                                       \
    if (DOG) stage_w32(wS, wsrc, cs, w, lane);                   \
  } while (0)

__global__ __launch_bounds__(256, 3) void mlp_fused_kernel(
    const float* __restrict__ feats,
    const float* __restrict__ b1g,
    const float* __restrict__ b2g,
    const float* __restrict__ b3g,
    const float* __restrict__ w4g,
    const float* __restrict__ b4g,
    const int*   __restrict__ sidxg,
    const f16*   __restrict__ w1t,
    const f16*   __restrict__ w2t,
    const f16*   __restrict__ w3t,
    float*       __restrict__ outg)
{
  __shared__ char arena[48 * 1024];
  char* aS0 = arena;                 // L1 features dbuf: 2 x 8 KB
  char* aS1 = arena + 8 * 1024;
  char* bS  = arena + 16 * 1024;     // L1 weights: single 32 KB (wave-private)
  char* hL  = arena;                 // hidden: h [64][256] fp16, 32 KB overlay
  char* wS  = arena + 32 * 1024;     // hidden weights: single 16 KB (wave-priv)

  const int s    = blockIdx.y;
  const int row0 = blockIdx.x * TM;
  const int t    = threadIdx.x;
  const int lane = t & 63;
  const int w    = t >> 6;           // 0..3; wave w owns output cols w*64..+63
  const int g    = lane >> 4;
  const int l15  = lane & 15;

  const int gr   = row0 + (t >> 2);
  const bool valid = gr < NPER;
  const int grc  = valid ? gr : (NPER - 1);
  const float* fsrcT = feats + ((size_t)s * NPER + grc) * NF + (t & 3) * 16;
  const char*  w1s   = (const char*)(w1t + (size_t)s * HID * NF);
  const char*  w2s   = (const char*)(w2t + (size_t)s * HID * HID);
  const char*  w3s   = (const char*)(w3t + (size_t)s * HID * HID);

  f32x4 acc[4][4];
  zero_acc(acc);

  // ===== L1 prologue: W1(0) gll; pa for chunks 1,2,3 in flight; A0 staged ==
  float4 pf[4], paA[4], paB[4], paC[4];
  load_pa(pf, fsrcT, 0);
  stage_w64(bS, w1s, 0, w, lane);
  load_pa(paA, fsrcT, 1);
  load_pa(paB, fsrcT, 2);
  load_pa(paC, fsrcT, 3);
  stage_feat64(aS0, pf, t);          // compiler-waits pf only
  WAIT_LGKM(); BARRIER();

  // ===== L1: 16 phases, KC=64, single-bS, 3-deep pa rotation =====
  // Queue at phase-c wait: [pa(c+2), gll(c), pa(c+3)] -> VM(4) steady.
  L1_STEP(0,  aS0, aS1, paA, 12, 1, 1);   // drain gll(0); paA <- 4
  L1_STEP(1,  aS1, aS0, paB,  4, 1, 1);   // drains pro paB/paC + gll(1)
  L1_STEP(2,  aS0, aS1, paC,  4, 1, 1);
  L1_STEP(3,  aS1, aS0, paA,  4, 1, 1);
  L1_STEP(4,  aS0, aS1, paB,  4, 1, 1);
  L1_STEP(5,  aS1, aS0, paC,  4, 1, 1);
  L1_STEP(6,  aS0, aS1, paA,  4, 1, 1);
  L1_STEP(7,  aS1, aS0, paB,  4, 1, 1);
  L1_STEP(8,  aS0, aS1, paC,  4, 1, 1);
  L1_STEP(9,  aS1, aS0, paA,  4, 1, 1);
  L1_STEP(10, aS0, aS1, paB,  4, 1, 1);
  L1_STEP(11, aS1, aS0, paC,  4, 1, 1);   // last refill: paC <- 15
  L1_STEP(12, aS0, aS1, paA,  4, 1, 0);   // stage A13
  L1_STEP(13, aS1, aS0, paB,  0, 1, 0);   // stage A14
  L1_STEP(14, aS0, aS1, paC,  0, 1, 0);   // stage A15; gll(15) issued
  { // phase 15: last chunk; no more staging into bS
    WAIT_VM(0); SCHED0();
    mfma64_a(acc, aS1, bS, w, g, l15);
    WAIT_LGKM(); BARRIER();               // all reads of bS/aS done
  }

  // ===== L1 -> L2: W2(0) gll into wS (dead bS-upper); h over dead 0..32K ==
  stage_w32(wS, w2s, 0, w, lane);
  silu_store(acc, b1g + s * HID, hL, w, lane);
  zero_acc(acc);
  WAIT_LGKM(); BARRIER();                 // hL published

  // ===== Layer 2: 8 chunks, KC=32, single-wS, barrier-free =====
  HID_ST(0, w2s, 1, 1);
  HID_ST(1, w2s, 2, 1);
  HID_ST(2, w2s, 3, 1);
  HID_ST(3, w2s, 4, 1);
  HID_ST(4, w2s, 5, 1);
  HID_ST(5, w2s, 6, 1);
  HID_ST(6, w2s, 7, 1);
  HID_ST(7, w3s, 0, 1);                   // cross into W3 prefetch
  BARRIER();                              // all waves done reading hL
  silu_store(acc, b2g + s * HID, hL, w, lane);
  zero_acc(acc);
  WAIT_LGKM(); BARRIER();                 // hL published

  // ===== Layer 3: 8 chunks =====
  HID_ST(0, w3s, 1, 1);
  HID_ST(1, w3s, 2, 1);
  HID_ST(2, w3s, 3, 1);
  HID_ST(3, w3s, 4, 1);
  HID_ST(4, w3s, 5, 1);
  HID_ST(5, w3s, 6, 1);
  HID_ST(6, w3s, 7, 1);
  HID_ST(7, w3s, 0, 0);                   // last chunk, no stage
  BARRIER();
  silu_store(acc, b3g + s * HID, hL, w, lane);
  WAIT_LGKM(); BARRIER();

  // ===== Layer 4: e = h @ W4 + b4; segment-sum via atomicAdd =====
  {
    const int row = t >> 2;
    const int q   = t & 3;
    const float* w4 = w4g + s * HID;
    float sum = 0.f;
    #pragma unroll
    for (int j8 = 0; j8 < 64; j8 += 8) {
      const int k = q * 64 + j8;
      f16x8 hv = *(const f16x8*)(hL + (((row * HID + k) * 2) ^ ((row & 7) << 4)));
      float4 wa = *(const float4*)(w4 + k);
      float4 wb = *(const float4*)(w4 + k + 4);
      sum += (float)hv[0] * wa.x + (float)hv[1] * wa.y + (float)hv[2] * wa.z + (float)hv[3] * wa.w
           + (float)hv[4] * wb.x + (float)hv[5] * wb.y + (float)hv[6] * wb.z + (float)hv[7] * wb.w;
    }
    sum += __shfl_xor(sum, 1);
    sum += __shfl_xor(sum, 2);
    if (q == 0 && valid) {
      atomicAdd(&outg[sidxg[s * NPER + gr]], sum + b4g[s]);
    }
  }
}

// ---------------------------------------------------------------------------
extern "C" void kernel_launch(void* const* d_in, const int* in_sizes, int n_in,
                              void* d_out, int out_size, void* d_ws, size_t ws_size,
                              hipStream_t stream)
{
  const float* feats = (const float*)d_in[0];
  const float* W1    = (const float*)d_in[1];
  const float* b1    = (const float*)d_in[2];
  const float* W2    = (const float*)d_in[3];
  const float* b2    = (const float*)d_in[4];
  const float* W3    = (const float*)d_in[5];
  const float* b3    = (const float*)d_in[6];
  const float* W4    = (const float*)d_in[7];
  const float* b4    = (const float*)d_in[8];
  const int*   sidx  = (const int*)d_in[9];
  float* out = (float*)d_out;

  f16* w1t = (f16*)d_ws;                              // [S][256][1024] fp16
  f16* w2t = w1t + (size_t)S_ * HID * NF;             // [S][256][256]  fp16
  f16* w3t = w2t + (size_t)S_ * HID * HID;            // [S][256][256]  fp16

  hipMemsetAsync(d_out, 0, NSTRUCT * sizeof(float), stream);
  transpose_all_kernel<<<dim3(16, 4, 12), 256, 0, stream>>>(W1, W2, W3, w1t, w2t, w3t);
  mlp_fused_kernel<<<dim3((NPER + TM - 1) / TM, S_), 256, 0, stream>>>(
      feats, b1, b2, b3, W4, b4, sidx, w1t, w2t, w3t, out);
}

// Round 8
// 183.050 us; speedup vs baseline: 1.0525x; 1.0525x over previous
//
#include <hip/hip_runtime.h>

typedef _Float16 f16;
typedef __attribute__((ext_vector_type(8))) _Float16 f16x8;
typedef __attribute__((ext_vector_type(4))) float f32x4;
typedef unsigned int u32;

#define S_      4
#define NPER    12500
#define NF      1024
#define HID     256
#define NSTRUCT 500
#define TM      128

#define GLB __attribute__((address_space(1)))
#define AS3 __attribute__((address_space(3)))

#define WAIT_VM(N)  asm volatile("s_waitcnt vmcnt(" #N ")" ::: "memory")
#define WAIT_LGKM() asm volatile("s_waitcnt lgkmcnt(0)" ::: "memory")
#define SCHED0()    __builtin_amdgcn_sched_barrier(0)
#define BARRIER()   do { __builtin_amdgcn_s_barrier(); SCHED0(); } while (0)

// ---------------------------------------------------------------------------
// Fused weight transpose + fp32->fp16 (all 3 layers, 1 launch) -- unchanged.
// ---------------------------------------------------------------------------
__global__ __launch_bounds__(256) void transpose_all_kernel(
    const float* __restrict__ W1, const float* __restrict__ W2,
    const float* __restrict__ W3,
    f16* __restrict__ w1t, f16* __restrict__ w2t, f16* __restrict__ w3t)
{
  const int z = blockIdx.z;            // layer*4 + species
  const int layer = z >> 2, sp = z & 3;
  const float* in; f16* out; int K;
  if (layer == 0)      { in = W1; out = w1t; K = NF;  }
  else if (layer == 1) { in = W2; out = w2t; K = HID; }
  else                 { in = W3; out = w3t; K = HID; }
  if (blockIdx.x * 64 >= K) return;

  __shared__ float tile[64][65];
  const float* inp = in + (size_t)sp * K * HID;
  f16* outp = out + (size_t)sp * K * HID;
  const int k0 = blockIdx.x * 64;
  const int n0 = blockIdx.y * 64;
  const int t = threadIdx.x;
  {
    const int lk = t >> 2;
    const int nq = (t & 3) * 16;
    const float* src = inp + (size_t)(k0 + lk) * HID + n0 + nq;
    #pragma unroll
    for (int i = 0; i < 4; ++i) {
      float4 v = *(const float4*)(src + i * 4);
      tile[lk][nq + i * 4 + 0] = v.x;
      tile[lk][nq + i * 4 + 1] = v.y;
      tile[lk][nq + i * 4 + 2] = v.z;
      tile[lk][nq + i * 4 + 3] = v.w;
    }
  }
  __syncthreads();
  {
    const int ln = t >> 2;
    const int kq = (t & 3) * 16;
    f16* dst = outp + (size_t)(n0 + ln) * K + k0 + kq;
    f16x8 a, b;
    #pragma unroll
    for (int j = 0; j < 8; ++j) a[j] = (f16)tile[kq + j][ln];
    #pragma unroll
    for (int j = 0; j < 8; ++j) b[j] = (f16)tile[kq + 8 + j][ln];
    *(f16x8*)dst = a;
    *(f16x8*)(dst + 8) = b;
  }
}

// ---------------------------------------------------------------------------
// Fused MLP R15: TM=128, 512 thr / 8 waves (2 row-groups x 4 col-groups).
// Per-wave tile = R13's exact 64x64 (acc[4][4], 32 MFMA/phase) -- phases stay
// FAT; the block carries 2x rows so 16 waves/CU and grid 392 <= 512 slots
// (single dispatch round vs R13's 1.53).
//  - aS: SINGLE 16K buffer [128r][64k] fp16, 2-barrier phase:
//      mfma -> lgkm -> BAR1 -> restage -> VM -> lgkm -> BAR2.
//  - bS: dbuf 2x32K, gll(c+2) issued mid-phase into just-freed buffer,
//    drained by VM before BAR2 (visibility to the PAIR-wave reader is via
//    the barrier, never via the partner's vmcnt).
//  - pa: 2 sets only (3rd set's cover was dead under in-order drain; saves
//    16 VGPR of spill margin -- R14 lesson).
//  - Hidden: hL [128][256] = 64K overlay; B in registers (R10-proven),
//    KC=32, 2-slot rotation, barrier-free inside layers.
//  - launch_bounds(512,4): need VGPR<=128 for 2 blocks/CU. Spill canary:
//    WRITE_SIZE.
// ---------------------------------------------------------------------------

__device__ __forceinline__ void zero_acc(f32x4 (&acc)[4][4]) {
  #pragma unroll
  for (int a = 0; a < 4; ++a)
    #pragma unroll
    for (int b = 0; b < 4; ++b)
      #pragma unroll
      for (int j = 0; j < 4; ++j) acc[a][b][j] = 0.f;
}

// L1 weights: bS [256 n][8 slots of 16B]; phys slot p at row r holds k-slot
// p^(r&7). 8 waves x 4 segs = 32 segs (1KB each).
__device__ __forceinline__ void stage_w64(char* bS, const char* wbase, int c,
                                          int w, int lane)
{
  #pragma unroll
  for (int i = 0; i < 4; ++i) {
    const int seg  = w * 4 + i;                 // 0..31
    const int rloc = lane >> 3;                 // 0..7
    const int p    = lane & 7;                  // phys 16B slot
    const int row  = seg * 8 + rloc;            // 0..255
    const int slog = p ^ rloc;                  // logical k-slot (row&7 == rloc)
    const char* gp = wbase + (size_t)row * (NF * 2) + (size_t)c * 128 + slog * 16;
    char* lp = bS + seg * 1024;                 // wave-uniform base
    __builtin_amdgcn_global_load_lds((const GLB u32*)gp, (AS3 u32*)lp, 16, 0, 0);
  }
}

// Features prefetch: thread t handles row t>>2 (0..127), floats (t&3)*16..+15.
__device__ __forceinline__ void load_pa(float4 (&pa)[4], const float* fsrcT, int c)
{
  #pragma unroll
  for (int j = 0; j < 4; ++j)
    pa[j] = *(const float4*)(fsrcT + c * 64 + j * 4);
}

// Features chunk [128 r][64 k] fp32->fp16 into aS (ds_write, R13 layout).
__device__ __forceinline__ void stage_feat64(char* aS, const float4 (&pa)[4], int t)
{
  const int r = t >> 2;                         // 0..127
  #pragma unroll
  for (int wr = 0; wr < 2; ++wr) {
    f16x8 hv;
    const float4 lo = pa[wr * 2 + 0], hi = pa[wr * 2 + 1];
    hv[0]=(f16)lo.x; hv[1]=(f16)lo.y; hv[2]=(f16)lo.z; hv[3]=(f16)lo.w;
    hv[4]=(f16)hi.x; hv[5]=(f16)hi.y; hv[6]=(f16)hi.z; hv[7]=(f16)hi.w;
    const int slog = (t & 3) * 2 + wr;
    const int p = slog ^ (r & 7);
    *(f16x8*)(aS + r * 128 + p * 16) = hv;
  }
}

// L1 compute: one KC=64 chunk, 32 MFMA. Wave (rgrp,cg): rows rgrp*64..+63,
// cols cg*64..+63.
__device__ __forceinline__ void mfma64_a(f32x4 (&acc)[4][4], const char* aS,
                                         const char* bS, int rgrp, int cg,
                                         int g, int l15)
{
  #pragma unroll
  for (int ks = 0; ks < 2; ++ks) {
    f16x8 af[4], bf[4];
    #pragma unroll
    for (int at = 0; at < 4; ++at) {
      const int rr = rgrp * 64 + at * 16 + l15;
      const int p  = (ks * 4 + g) ^ (rr & 7);
      af[at] = *(const f16x8*)(aS + rr * 128 + p * 16);
    }
    #pragma unroll
    for (int bt = 0; bt < 4; ++bt) {
      const int nn = cg * 64 + bt * 16 + l15;
      const int p  = (ks * 4 + g) ^ (nn & 7);
      bf[bt] = *(const f16x8*)(bS + nn * 128 + p * 16);
    }
    #pragma unroll
    for (int at = 0; at < 4; ++at)
      #pragma unroll
      for (int bt = 0; bt < 4; ++bt)
        acc[at][bt] = __builtin_amdgcn_mfma_f32_16x16x32_f16(af[at], bf[bt], acc[at][bt], 0, 0, 0);
  }
}

// Hidden B fragments L2 -> regs: 4 x 16B per lane per KC=32 chunk.
__device__ __forceinline__ void load_bh(f16x8 (&bf)[4], const f16* wsrc, int c,
                                        int cg, int g, int l15)
{
  #pragma unroll
  for (int bt = 0; bt < 4; ++bt) {
    const int nn = cg * 64 + bt * 16 + l15;
    bf[bt] = *(const f16x8*)(wsrc + (size_t)nn * HID + c * 32 + g * 8);
  }
}

// Hidden compute: KC=32 chunk, A = hL fp16 (xor (row&7)<<4 layout), B regs.
__device__ __forceinline__ void mfma32_h(f32x4 (&acc)[4][4], const char* hL, int c,
                                         const f16x8 (&bf)[4], int rgrp,
                                         int g, int l15)
{
  f16x8 af[4];
  #pragma unroll
  for (int at = 0; at < 4; ++at) {
    const int rr = rgrp * 64 + at * 16 + l15;
    af[at] = *(const f16x8*)(hL + ((rr * 512 + c * 64 + g * 16) ^ ((rr & 7) << 4)));
  }
  #pragma unroll
  for (int at = 0; at < 4; ++at)
    #pragma unroll
    for (int bt = 0; bt < 4; ++bt)
      acc[at][bt] = __builtin_amdgcn_mfma_f32_16x16x32_f16(af[at], bf[bt], acc[at][bt], 0, 0, 0);
}

__device__ __forceinline__ void silu_store(f32x4 (&acc)[4][4],
                                           const float* __restrict__ bias,
                                           char* hL, int rgrp, int cg, int lane)
{
  const int g = lane >> 4, l15 = lane & 15;
  #pragma unroll
  for (int bt = 0; bt < 4; ++bt) {
    const int col = cg * 64 + bt * 16 + l15;
    const float b = bias[col];
    #pragma unroll
    for (int at = 0; at < 4; ++at) {
      #pragma unroll
      for (int j = 0; j < 4; ++j) {
        const int row = rgrp * 64 + at * 16 + g * 4 + j;  // m89-verified C/D map
        float x = acc[at][bt][j] + b;
        x = x * __builtin_amdgcn_rcpf(1.f + __expf(-x));
        *(f16*)(hL + (((row * HID + col) * 2) ^ ((row & 7) << 4))) = (f16)x;
      }
    }
  }
}

// L1 phase c: compute chunk c (aS + bS[c&1]); BAR1 (reads done); restage
// aS<-feat(c+1) from PAset; refill PAset<-pa(c+3); gll W1(c+2) into the
// just-freed bS buffer; VM drains gll(c+1) (issued LAST phase => ~1 full
// phase of L2 cover) pre-BAR2 so the barrier publishes it to the pair wave.
#define L1_PH(c, BSc, PAset, DOPA, DOG, VMN)                     \
  do {                                                           \
    mfma64_a(acc, aS, BSc, rgrp, cg, g, l15);                    \
    WAIT_LGKM(); BARRIER();                                      \
    stage_feat64(aS, PAset, t);                                  \
    if (DOPA) load_pa(PAset, fsrcT, (c) + 3);                    \
    if (DOG)  stage_w64(BSc, w1s, (c) + 2, w, lane);             \
    WAIT_VM(VMN); SCHED0();                                      \
    WAIT_LGKM(); BARRIER();                                      \
  } while (0)

__global__ __launch_bounds__(512, 4) void mlp_fused_kernel(
    const float* __restrict__ feats,
    const float* __restrict__ b1g,
    const float* __restrict__ b2g,
    const float* __restrict__ b3g,
    const float* __restrict__ w4g,
    const float* __restrict__ b4g,
    const int*   __restrict__ sidxg,
    const f16*   __restrict__ w1t,
    const f16*   __restrict__ w2t,
    const f16*   __restrict__ w3t,
    float*       __restrict__ outg)
{
  __shared__ char arena[80 * 1024];
  char* aS  = arena;                 // L1 features: single 16 KB
  char* bS0 = arena + 16 * 1024;     // L1 weights dbuf: 2 x 32 KB
  char* bS1 = arena + 48 * 1024;
  char* hL  = arena;                 // hidden: h [128][256] fp16, 64 KB overlay

  const int s    = blockIdx.y;
  const int row0 = blockIdx.x * TM;
  const int t    = threadIdx.x;
  const int lane = t & 63;
  const int w    = t >> 6;           // 0..7
  const int rgrp = w >> 2;           // row-group: rows rgrp*64..+63
  const int cg   = w & 3;            // col-group: cols cg*64..+63
  const int g    = lane >> 4;
  const int l15  = lane & 15;

  const int gr   = row0 + (t >> 2);  // staging/L4 row of this thread (0..127)
  const bool valid = gr < NPER;
  const int grc  = valid ? gr : (NPER - 1);
  const float* fsrcT = feats + ((size_t)s * NPER + grc) * NF + (t & 3) * 16;
  const char*  w1s   = (const char*)(w1t + (size_t)s * HID * NF);
  const f16*   w2s   = w2t + (size_t)s * HID * HID;
  const f16*   w3s   = w3t + (size_t)s * HID * HID;

  f32x4 acc[4][4];
  f16x8 bfA[4], bfB[4];
  zero_acc(acc);

  // ===== L1 prologue: W1(0),W1(1) gll; pa(1),pa(2); A(0) staged =====
  float4 pf[4], paA[4], paB[4];
  load_pa(pf,  fsrcT, 0);
  load_pa(paA, fsrcT, 1);
  load_pa(paB, fsrcT, 2);
  stage_w64(bS0, w1s, 0, w, lane);
  stage_w64(bS1, w1s, 1, w, lane);
  stage_feat64(aS, pf, t);           // compiler-waits pf only
  WAIT_VM(4); SCHED0();              // drain gll(0) (+prologue pa); keep gll(1)
  WAIT_LGKM(); BARRIER();

  // ===== L1: 16 phases, KC=64, single aS, dbuf bS, 2-set pa =====
  L1_PH(0,  bS0, paA, 1, 1, 8);
  L1_PH(1,  bS1, paB, 1, 1, 8);
  L1_PH(2,  bS0, paA, 1, 1, 8);
  L1_PH(3,  bS1, paB, 1, 1, 8);
  L1_PH(4,  bS0, paA, 1, 1, 8);
  L1_PH(5,  bS1, paB, 1, 1, 8);
  L1_PH(6,  bS0, paA, 1, 1, 8);
  L1_PH(7,  bS1, paB, 1, 1, 8);
  L1_PH(8,  bS0, paA, 1, 1, 8);
  L1_PH(9,  bS1, paB, 1, 1, 8);
  L1_PH(10, bS0, paA, 1, 1, 8);
  L1_PH(11, bS1, paB, 1, 1, 8);
  L1_PH(12, bS0, paA, 1, 1, 8);      // last pa refill: paA <- pa(15)
  L1_PH(13, bS1, paB, 0, 1, 4);      // gll(15); drain gll(14)
  L1_PH(14, bS0, paA, 0, 0, 0);      // stage feat(15); drain gll(15)
  { // phase 15: compute chunk 15; prefetch hidden W2(0),W2(1) into regs
    mfma64_a(acc, aS, bS1, rgrp, cg, g, l15);
    load_bh(bfA, w2s, 0, cg, g, l15);
    load_bh(bfB, w2s, 1, cg, g, l15);
    WAIT_LGKM(); BARRIER();          // all reads of aS/bS done
  }

  // ===== L1 -> L2: write h over dead aS/bS =====
  silu_store(acc, b1g + s * HID, hL, rgrp, cg, lane);
  zero_acc(acc);
  WAIT_LGKM(); BARRIER();            // hL published

  // ===== Layer 2: 8 chunks KC=32, barrier-free, 2-slot reg B =====
  mfma32_h(acc, hL, 0, bfA, rgrp, g, l15);  load_bh(bfA, w2s, 2, cg, g, l15);
  mfma32_h(acc, hL, 1, bfB, rgrp, g, l15);  load_bh(bfB, w2s, 3, cg, g, l15);
  mfma32_h(acc, hL, 2, bfA, rgrp, g, l15);  load_bh(bfA, w2s, 4, cg, g, l15);
  mfma32_h(acc, hL, 3, bfB, rgrp, g, l15);  load_bh(bfB, w2s, 5, cg, g, l15);
  mfma32_h(acc, hL, 4, bfA, rgrp, g, l15);  load_bh(bfA, w2s, 6, cg, g, l15);
  mfma32_h(acc, hL, 5, bfB, rgrp, g, l15);  load_bh(bfB, w2s, 7, cg, g, l15);
  mfma32_h(acc, hL, 6, bfA, rgrp, g, l15);  load_bh(bfA, w3s, 0, cg, g, l15);
  mfma32_h(acc, hL, 7, bfB, rgrp, g, l15);  load_bh(bfB, w3s, 1, cg, g, l15);
  BARRIER();                         // all waves done reading hL
  silu_store(acc, b2g + s * HID, hL, rgrp, cg, lane);
  zero_acc(acc);
  WAIT_LGKM(); BARRIER();            // hL published

  // ===== Layer 3: 8 chunks, barrier-free =====
  mfma32_h(acc, hL, 0, bfA, rgrp, g, l15);  load_bh(bfA, w3s, 2, cg, g, l15);
  mfma32_h(acc, hL, 1, bfB, rgrp, g, l15);  load_bh(bfB, w3s, 3, cg, g, l15);
  mfma32_h(acc, hL, 2, bfA, rgrp, g, l15);  load_bh(bfA, w3s, 4, cg, g, l15);
  mfma32_h(acc, hL, 3, bfB, rgrp, g, l15);  load_bh(bfB, w3s, 5, cg, g, l15);
  mfma32_h(acc, hL, 4, bfA, rgrp, g, l15);  load_bh(bfA, w3s, 6, cg, g, l15);
  mfma32_h(acc, hL, 5, bfB, rgrp, g, l15);  load_bh(bfB, w3s, 7, cg, g, l15);
  mfma32_h(acc, hL, 6, bfA, rgrp, g, l15);
  mfma32_h(acc, hL, 7, bfB, rgrp, g, l15);
  BARRIER();
  silu_store(acc, b3g + s * HID, hL, rgrp, cg, lane);
  WAIT_LGKM(); BARRIER();

  // ===== Layer 4: e = h @ W4 + b4; segment-sum via atomicAdd =====
  {
    const int row = t >> 2;          // 0..127
    const int q   = t & 3;
    const float* w4 = w4g + s * HID;
    float sum = 0.f;
    #pragma unroll
    for (int j8 = 0; j8 < 64; j8 += 8) {
      const int k = q * 64 + j8;
      f16x8 hv = *(const f16x8*)(hL + (((row * HID + k) * 2) ^ ((row & 7) << 4)));
      float4 wa = *(const float4*)(w4 + k);
      float4 wb = *(const float4*)(w4 + k + 4);
      sum += (float)hv[0] * wa.x + (float)hv[1] * wa.y + (float)hv[2] * wa.z + (float)hv[3] * wa.w
           + (float)hv[4] * wb.x + (float)hv[5] * wb.y + (float)hv[6] * wb.z + (float)hv[7] * wb.w;
    }
    sum += __shfl_xor(sum, 1);
    sum += __shfl_xor(sum, 2);
    if (q == 0 && valid) {
      atomicAdd(&outg[sidxg[s * NPER + gr]], sum + b4g[s]);
    }
  }
}

// ---------------------------------------------------------------------------
extern "C" void kernel_launch(void* const* d_in, const int* in_sizes, int n_in,
                              void* d_out, int out_size, void* d_ws, size_t ws_size,
                              hipStream_t stream)
{
  const float* feats = (const float*)d_in[0];
  const float* W1    = (const float*)d_in[1];
  const float* b1    = (const float*)d_in[2];
  const float* W2    = (const float*)d_in[3];
  const float* b2    = (const float*)d_in[4];
  const float* W3    = (const float*)d_in[5];
  const float* b3    = (const float*)d_in[6];
  const float* W4    = (const float*)d_in[7];
  const float* b4    = (const float*)d_in[8];
  const int*   sidx  = (const int*)d_in[9];
  float* out = (float*)d_out;

  f16* w1t = (f16*)d_ws;                              // [S][256][1024] fp16
  f16* w2t = w1t + (size_t)S_ * HID * NF;             // [S][256][256]  fp16
  f16* w3t = w2t + (size_t)S_ * HID * HID;            // [S][256][256]  fp16

  hipMemsetAsync(d_out, 0, NSTRUCT * sizeof(float), stream);
  transpose_all_kernel<<<dim3(16, 4, 12), 256, 0, stream>>>(W1, W2, W3, w1t, w2t, w3t);
  mlp_fused_kernel<<<dim3((NPER + TM - 1) / TM, S_), 512, 0, stream>>>(
      feats, b1, b2, b3, W4, b4, sidx, w1t, w2t, w3t, out);
}

// Round 9
// 117.269 us; speedup vs baseline: 1.6428x; 1.5609x over previous
//
#include <hip/hip_runtime.h>

typedef _Float16 f16;
typedef __attribute__((ext_vector_type(8))) _Float16 f16x8;
typedef __attribute__((ext_vector_type(4))) float f32x4;
typedef unsigned int u32;

#define S_      4
#define NPER    12500
#define NF      1024
#define HID     256
#define NSTRUCT 500
#define TM      64

#define GLB __attribute__((address_space(1)))
#define AS3 __attribute__((address_space(3)))

#define WAIT_VM(N)  asm volatile("s_waitcnt vmcnt(" #N ")" ::: "memory")
#define WAIT_LGKM() asm volatile("s_waitcnt lgkmcnt(0)" ::: "memory")
#define SCHED0()    __builtin_amdgcn_sched_barrier(0)
#define BARRIER()   do { __builtin_amdgcn_s_barrier(); SCHED0(); } while (0)

// ---------------------------------------------------------------------------
// Fused weight transpose + fp32->fp16 (all 3 layers, 1 launch)
// ---------------------------------------------------------------------------
__global__ __launch_bounds__(256) void transpose_all_kernel(
    const float* __restrict__ W1, const float* __restrict__ W2,
    const float* __restrict__ W3,
    f16* __restrict__ w1t, f16* __restrict__ w2t, f16* __restrict__ w3t)
{
  const int z = blockIdx.z;            // layer*4 + species
  const int layer = z >> 2, sp = z & 3;
  const float* in; f16* out; int K;
  if (layer == 0)      { in = W1; out = w1t; K = NF;  }
  else if (layer == 1) { in = W2; out = w2t; K = HID; }
  else                 { in = W3; out = w3t; K = HID; }
  if (blockIdx.x * 64 >= K) return;

  __shared__ float tile[64][65];
  const float* inp = in + (size_t)sp * K * HID;
  f16* outp = out + (size_t)sp * K * HID;
  const int k0 = blockIdx.x * 64;
  const int n0 = blockIdx.y * 64;
  const int t = threadIdx.x;
  {
    const int lk = t >> 2;
    const int nq = (t & 3) * 16;
    const float* src = inp + (size_t)(k0 + lk) * HID + n0 + nq;
    #pragma unroll
    for (int i = 0; i < 4; ++i) {
      float4 v = *(const float4*)(src + i * 4);
      tile[lk][nq + i * 4 + 0] = v.x;
      tile[lk][nq + i * 4 + 1] = v.y;
      tile[lk][nq + i * 4 + 2] = v.z;
      tile[lk][nq + i * 4 + 3] = v.w;
    }
  }
  __syncthreads();
  {
    const int ln = t >> 2;
    const int kq = (t & 3) * 16;
    f16* dst = outp + (size_t)(n0 + ln) * K + k0 + kq;
    f16x8 a, b;
    #pragma unroll
    for (int j = 0; j < 8; ++j) a[j] = (f16)tile[kq + j][ln];
    #pragma unroll
    for (int j = 0; j < 8; ++j) b[j] = (f16)tile[kq + 8 + j][ln];
    *(f16x8*)dst = a;
    *(f16x8*)(dst + 8) = b;
  }
}

// ---------------------------------------------------------------------------
// Fused MLP R16 = R13 (best, 108.3us) + hidden-layer B in registers:
//  - L1: R13 VERBATIM. 16 fat phases KC=64, aS fp16 dbuf (reg-staged pa,
//    3-set rotation, ~3-phase HBM cover), bS gll dbuf (1-phase L2 cover),
//    steady VM(16), 1 barrier/phase.
//  - Hidden: B L2->registers, 2-set rotation, distance-2 prefetch (~2 thin
//    chunks ~300cy >= L2 ~250cy). Removes wS LDS traffic + the manual
//    WAIT_VM(8) queue-drain per chunk (compiler emits per-register counted
//    waits). R10/R15-proven mechanics. Barrier-free inside layers.
//  - Registers: acc 64 AGPR + arch ~116 + bf 32 = ~212 <= 256 at (256,2).
//    Spill canary: WRITE_SIZE.
// ---------------------------------------------------------------------------

__device__ __forceinline__ void zero_acc(f32x4 (&acc)[4][4]) {
  #pragma unroll
  for (int a = 0; a < 4; ++a)
    #pragma unroll
    for (int b = 0; b < 4; ++b)
      #pragma unroll
      for (int j = 0; j < 4; ++j) acc[a][b][j] = 0.f;
}

// L1 weights: bS [256 n][8 slots of 16B]; phys slot p at row r holds k-slot
// p^(r&7). Wave w stages rows w*64..+63 -- the rows it alone reads.
__device__ __forceinline__ void stage_w64(char* bS, const char* wbase, int c,
                                          int w, int lane)
{
  #pragma unroll
  for (int i = 0; i < 8; ++i) {
    const int seg  = w * 8 + i;                 // 0..31
    const int rloc = lane >> 3;                 // 0..7
    const int p    = lane & 7;                  // phys 16B slot
    const int row  = seg * 8 + rloc;            // 0..255
    const int slog = p ^ rloc;                  // logical k-slot (row&7 == rloc)
    const char* gp = wbase + (size_t)row * (NF * 2) + (size_t)c * 128 + slog * 16;
    char* lp = bS + seg * 1024;                 // wave-uniform base
    __builtin_amdgcn_global_load_lds((const GLB u32*)gp, (AS3 u32*)lp, 16, 0, 0);
  }
}

__device__ __forceinline__ void load_pa(float4 (&pa)[4], const float* fsrcT, int c)
{
  #pragma unroll
  for (int j = 0; j < 4; ++j)
    pa[j] = *(const float4*)(fsrcT + c * 64 + j * 4);
}

// Features chunk [64 r][64 k] fp32->fp16 into aS (ds_write).
__device__ __forceinline__ void stage_feat64(char* aS, const float4 (&pa)[4], int t)
{
  const int r = t >> 2;
  #pragma unroll
  for (int wr = 0; wr < 2; ++wr) {
    f16x8 hv;
    const float4 lo = pa[wr * 2 + 0], hi = pa[wr * 2 + 1];
    hv[0]=(f16)lo.x; hv[1]=(f16)lo.y; hv[2]=(f16)lo.z; hv[3]=(f16)lo.w;
    hv[4]=(f16)hi.x; hv[5]=(f16)hi.y; hv[6]=(f16)hi.z; hv[7]=(f16)hi.w;
    const int slog = (t & 3) * 2 + wr;
    const int p = slog ^ (r & 7);
    *(f16x8*)(aS + r * 128 + p * 16) = hv;
  }
}

// L1 compute: one KC=64 chunk, 32 MFMA.
__device__ __forceinline__ void mfma64_a(f32x4 (&acc)[4][4], const char* aS,
                                         const char* bS, int w, int g, int l15)
{
  #pragma unroll
  for (int ks = 0; ks < 2; ++ks) {
    f16x8 af[4], bf[4];
    #pragma unroll
    for (int at = 0; at < 4; ++at) {
      const int rr = at * 16 + l15;
      const int p  = (ks * 4 + g) ^ (rr & 7);
      af[at] = *(const f16x8*)(aS + rr * 128 + p * 16);
    }
    #pragma unroll
    for (int bt = 0; bt < 4; ++bt) {
      const int nn = w * 64 + bt * 16 + l15;
      const int p  = (ks * 4 + g) ^ (nn & 7);
      bf[bt] = *(const f16x8*)(bS + nn * 128 + p * 16);
    }
    #pragma unroll
    for (int at = 0; at < 4; ++at)
      #pragma unroll
      for (int bt = 0; bt < 4; ++bt)
        acc[at][bt] = __builtin_amdgcn_mfma_f32_16x16x32_f16(af[at], bf[bt], acc[at][bt], 0, 0, 0);
  }
}

// Hidden B fragments L2 -> regs: 4 x 16B per lane per KC=32 chunk.
// frag bt: col nn = w*64+bt*16+l15, k = c*32 + g*8 .. +7.
__device__ __forceinline__ void load_bh(f16x8 (&bf)[4], const f16* wsrc, int c,
                                        int w, int g, int l15)
{
  #pragma unroll
  for (int bt = 0; bt < 4; ++bt) {
    const int nn = w * 64 + bt * 16 + l15;
    bf[bt] = *(const f16x8*)(wsrc + (size_t)nn * HID + c * 32 + g * 8);
  }
}

// Hidden compute: one KC=32 chunk, 16 MFMA; A = hL fp16, B regs.
__device__ __forceinline__ void mfma32_h(f32x4 (&acc)[4][4], const char* hL, int c,
                                         const f16x8 (&bf)[4], int g, int l15)
{
  f16x8 af[4];
  #pragma unroll
  for (int at = 0; at < 4; ++at) {
    const int rr = at * 16 + l15;
    af[at] = *(const f16x8*)(hL + ((rr * 512 + c * 64 + g * 16) ^ ((rr & 7) << 4)));
  }
  #pragma unroll
  for (int at = 0; at < 4; ++at)
    #pragma unroll
    for (int bt = 0; bt < 4; ++bt)
      acc[at][bt] = __builtin_amdgcn_mfma_f32_16x16x32_f16(af[at], bf[bt], acc[at][bt], 0, 0, 0);
}

__device__ __forceinline__ void silu_store(f32x4 (&acc)[4][4],
                                           const float* __restrict__ bias,
                                           char* hL, int w, int lane)
{
  const int g = lane >> 4, l15 = lane & 15;
  #pragma unroll
  for (int bt = 0; bt < 4; ++bt) {
    const int col = w * 64 + bt * 16 + l15;
    const float b = bias[col];
    #pragma unroll
    for (int at = 0; at < 4; ++at) {
      #pragma unroll
      for (int j = 0; j < 4; ++j) {
        const int row = at * 16 + g * 4 + j;   // m89-verified C/D mapping
        float x = acc[at][bt][j] + b;
        x = x * __builtin_amdgcn_rcpf(1.f + __expf(-x));
        *(f16*)(hL + (((row * HID + col) * 2) ^ ((row & 7) << 4))) = (f16)x;
      }
    }
  }
}

// L1 phase (R13 verbatim): stage feat(c+1) from PAset, gll W1(c+1), refill
// PAset <- pa(c+4), counted wait (forces own gll(c)), compute c, publish.
#define L1_STEP(c, ASc, ASn, BSc, BSn, PAset, VMN, DOG, DOPA)   \
  do {                                                           \
    stage_feat64(ASn, PAset, t);                                 \
    if (DOG)  stage_w64(BSn, w1s, (c) + 1, w, lane);             \
    if (DOPA) load_pa(PAset, fsrcT, (c) + 4);                    \
    WAIT_VM(VMN); SCHED0();                                      \
    mfma64_a(acc, ASc, BSc, w, g, l15);                          \
    WAIT_LGKM(); BARRIER();                                      \
  } while (0)

__global__ __launch_bounds__(256, 2) void mlp_fused_kernel(
    const float* __restrict__ feats,
    const float* __restrict__ b1g,
    const float* __restrict__ b2g,
    const float* __restrict__ b3g,
    const float* __restrict__ w4g,
    const float* __restrict__ b4g,
    const int*   __restrict__ sidxg,
    const f16*   __restrict__ w1t,
    const f16*   __restrict__ w2t,
    const f16*   __restrict__ w3t,
    float*       __restrict__ outg)
{
  __shared__ char arena[80 * 1024];
  char* aS0 = arena;                 // L1 features dbuf: 2 x 8 KB
  char* aS1 = arena + 8 * 1024;
  char* bS0 = arena + 16 * 1024;     // L1 weights dbuf: 2 x 32 KB
  char* bS1 = arena + 48 * 1024;
  char* hL  = arena;                 // hidden: h [64][256] fp16, 32 KB overlay

  const int s    = blockIdx.y;
  const int row0 = blockIdx.x * TM;
  const int t    = threadIdx.x;
  const int lane = t & 63;
  const int w    = t >> 6;           // 0..3; wave w owns output cols w*64..+63
  const int g    = lane >> 4;
  const int l15  = lane & 15;

  const int gr   = row0 + (t >> 2);
  const bool valid = gr < NPER;
  const int grc  = valid ? gr : (NPER - 1);
  const float* fsrcT = feats + ((size_t)s * NPER + grc) * NF + (t & 3) * 16;
  const char*  w1s   = (const char*)(w1t + (size_t)s * HID * NF);
  const f16*   w2s   = w2t + (size_t)s * HID * HID;
  const f16*   w3s   = w3t + (size_t)s * HID * HID;

  f32x4 acc[4][4];
  f16x8 bfA[4], bfB[4];              // hidden B regs (live from L1 phase 15)
  zero_acc(acc);

  // ===== L1 prologue: chunk 0 staged; pa for chunks 1,2,3 in flight =====
  float4 pf[4], paA[4], paB[4], paC[4];
  load_pa(pf, fsrcT, 0);
  stage_w64(bS0, w1s, 0, w, lane);
  load_pa(paA, fsrcT, 1);
  load_pa(paB, fsrcT, 2);
  load_pa(paC, fsrcT, 3);
  stage_feat64(aS0, pf, t);          // compiler-waits pf
  WAIT_LGKM(); BARRIER();

  // ===== L1: 16 phases, KC=64, 3-deep pa rotation, steady VM(16) =====
  L1_STEP(0,  aS0, aS1, bS0, bS1, paA, 20, 1, 1);
  L1_STEP(1,  aS1, aS0, bS1, bS0, paB, 16, 1, 1);
  L1_STEP(2,  aS0, aS1, bS0, bS1, paC, 16, 1, 1);
  L1_STEP(3,  aS1, aS0, bS1, bS0, paA, 16, 1, 1);
  L1_STEP(4,  aS0, aS1, bS0, bS1, paB, 16, 1, 1);
  L1_STEP(5,  aS1, aS0, bS1, bS0, paC, 16, 1, 1);
  L1_STEP(6,  aS0, aS1, bS0, bS1, paA, 16, 1, 1);
  L1_STEP(7,  aS1, aS0, bS1, bS0, paB, 16, 1, 1);
  L1_STEP(8,  aS0, aS1, bS0, bS1, paC, 16, 1, 1);
  L1_STEP(9,  aS1, aS0, bS1, bS0, paA, 16, 1, 1);
  L1_STEP(10, aS0, aS1, bS0, bS1, paB, 16, 1, 1);
  L1_STEP(11, aS1, aS0, bS1, bS0, paC, 16, 1, 1);   // last refill: paC <- 15
  L1_STEP(12, aS0, aS1, bS0, bS1, paA, 12, 1, 0);   // consume pa(13)
  L1_STEP(13, aS1, aS0, bS1, bS0, paB,  8, 1, 0);   // consume pa(14)
  L1_STEP(14, aS0, aS1, bS0, bS1, paC,  8, 1, 0);   // consume pa(15); bS1<-15
  { // phase 15: early-issue W2 chunks 0,1 into regs; drain gll(15); compute
    load_bh(bfA, w2s, 0, w, g, l15);
    load_bh(bfB, w2s, 1, w, g, l15);
    WAIT_VM(8); SCHED0();            // drains gll(15); keeps bfA,bfB in flight
    mfma64_a(acc, aS1, bS1, w, g, l15);
    WAIT_LGKM(); BARRIER();
  }

  // ===== L1 -> L2: write h over dead aS/bS0-lower =====
  silu_store(acc, b1g + s * HID, hL, w, lane);
  zero_acc(acc);
  WAIT_LGKM(); BARRIER();            // hL published

  // ===== Layer 2: 8 chunks KC=32, barrier-free, reg-B distance-2 =====
  mfma32_h(acc, hL, 0, bfA, g, l15);  load_bh(bfA, w2s, 2, w, g, l15);
  mfma32_h(acc, hL, 1, bfB, g, l15);  load_bh(bfB, w2s, 3, w, g, l15);
  mfma32_h(acc, hL, 2, bfA, g, l15);  load_bh(bfA, w2s, 4, w, g, l15);
  mfma32_h(acc, hL, 3, bfB, g, l15);  load_bh(bfB, w2s, 5, w, g, l15);
  mfma32_h(acc, hL, 4, bfA, g, l15);  load_bh(bfA, w2s, 6, w, g, l15);
  mfma32_h(acc, hL, 5, bfB, g, l15);  load_bh(bfB, w2s, 7, w, g, l15);
  mfma32_h(acc, hL, 6, bfA, g, l15);  load_bh(bfA, w3s, 0, w, g, l15);
  mfma32_h(acc, hL, 7, bfB, g, l15);  load_bh(bfB, w3s, 1, w, g, l15);
  BARRIER();                         // all waves done reading hL
  silu_store(acc, b2g + s * HID, hL, w, lane);
  zero_acc(acc);
  WAIT_LGKM(); BARRIER();            // hL published

  // ===== Layer 3: 8 chunks, barrier-free =====
  mfma32_h(acc, hL, 0, bfA, g, l15);  load_bh(bfA, w3s, 2, w, g, l15);
  mfma32_h(acc, hL, 1, bfB, g, l15);  load_bh(bfB, w3s, 3, w, g, l15);
  mfma32_h(acc, hL, 2, bfA, g, l15);  load_bh(bfA, w3s, 4, w, g, l15);
  mfma32_h(acc, hL, 3, bfB, g, l15);  load_bh(bfB, w3s, 5, w, g, l15);
  mfma32_h(acc, hL, 4, bfA, g, l15);  load_bh(bfA, w3s, 6, w, g, l15);
  mfma32_h(acc, hL, 5, bfB, g, l15);  load_bh(bfB, w3s, 7, w, g, l15);
  mfma32_h(acc, hL, 6, bfA, g, l15);
  mfma32_h(acc, hL, 7, bfB, g, l15);
  BARRIER();
  silu_store(acc, b3g + s * HID, hL, w, lane);
  WAIT_LGKM(); BARRIER();

  // ===== Layer 4: e = h @ W4 + b4; segment-sum via atomicAdd =====
  {
    const int row = t >> 2;
    const int q   = t & 3;
    const float* w4 = w4g + s * HID;
    float sum = 0.f;
    #pragma unroll
    for (int j8 = 0; j8 < 64; j8 += 8) {
      const int k = q * 64 + j8;
      f16x8 hv = *(const f16x8*)(hL + (((row * HID + k) * 2) ^ ((row & 7) << 4)));
      float4 wa = *(const float4*)(w4 + k);
      float4 wb = *(const float4*)(w4 + k + 4);
      sum += (float)hv[0] * wa.x + (float)hv[1] * wa.y + (float)hv[2] * wa.z + (float)hv[3] * wa.w
           + (float)hv[4] * wb.x + (float)hv[5] * wb.y + (float)hv[6] * wb.z + (float)hv[7] * wb.w;
    }
    sum += __shfl_xor(sum, 1);
    sum += __shfl_xor(sum, 2);
    if (q == 0 && valid) {
      atomicAdd(&outg[sidxg[s * NPER + gr]], sum + b4g[s]);
    }
  }
}

// ---------------------------------------------------------------------------
extern "C" void kernel_launch(void* const* d_in, const int* in_sizes, int n_in,
                              void* d_out, int out_size, void* d_ws, size_t ws_size,
                              hipStream_t stream)
{
  const float* feats = (const float*)d_in[0];
  const float* W1    = (const float*)d_in[1];
  const float* b1    = (const float*)d_in[2];
  const float* W2    = (const float*)d_in[3];
  const float* b2    = (const float*)d_in[4];
  const float* W3    = (const float*)d_in[5];
  const float* b3    = (const float*)d_in[6];
  const float* W4    = (const float*)d_in[7];
  const float* b4    = (const float*)d_in[8];
  const int*   sidx  = (const int*)d_in[9];
  float* out = (float*)d_out;

  f16* w1t = (f16*)d_ws;                              // [S][256][1024] fp16
  f16* w2t = w1t + (size_t)S_ * HID * NF;             // [S][256][256]  fp16
  f16* w3t = w2t + (size_t)S_ * HID * HID;            // [S][256][256]  fp16

  hipMemsetAsync(d_out, 0, NSTRUCT * sizeof(float), stream);
  transpose_all_kernel<<<dim3(16, 4, 12), 256, 0, stream>>>(W1, W2, W3, w1t, w2t, w3t);
  mlp_fused_kernel<<<dim3((NPER + TM - 1) / TM, S_), 256, 0, stream>>>(
      feats, b1, b2, b3, W4, b4, sidx, w1t, w2t, w3t, out);
}

// Round 10
// 104.035 us; speedup vs baseline: 1.8518x; 1.1272x over previous
//
#include <hip/hip_runtime.h>

typedef _Float16 f16;
typedef __attribute__((ext_vector_type(8))) _Float16 f16x8;
typedef __attribute__((ext_vector_type(4))) float f32x4;
typedef unsigned int u32;

#define S_      4
#define NPER    12500
#define NF      1024
#define HID     256
#define NSTRUCT 500
#define TM      64

#define GLB __attribute__((address_space(1)))
#define AS3 __attribute__((address_space(3)))

#define WAIT_VM(N)  asm volatile("s_waitcnt vmcnt(" #N ")" ::: "memory")
#define WAIT_LGKM() asm volatile("s_waitcnt lgkmcnt(0)" ::: "memory")
#define SCHED0()    __builtin_amdgcn_sched_barrier(0)
#define BARRIER()   do { __builtin_amdgcn_s_barrier(); SCHED0(); } while (0)

// ---------------------------------------------------------------------------
// Fused weight transpose + fp32->fp16 (all 3 layers, 1 launch)
// ---------------------------------------------------------------------------
__global__ __launch_bounds__(256) void transpose_all_kernel(
    const float* __restrict__ W1, const float* __restrict__ W2,
    const float* __restrict__ W3,
    f16* __restrict__ w1t, f16* __restrict__ w2t, f16* __restrict__ w3t)
{
  const int z = blockIdx.z;            // layer*4 + species
  const int layer = z >> 2, sp = z & 3;
  const float* in; f16* out; int K;
  if (layer == 0)      { in = W1; out = w1t; K = NF;  }
  else if (layer == 1) { in = W2; out = w2t; K = HID; }
  else                 { in = W3; out = w3t; K = HID; }
  if (blockIdx.x * 64 >= K) return;

  __shared__ float tile[64][65];
  const float* inp = in + (size_t)sp * K * HID;
  f16* outp = out + (size_t)sp * K * HID;
  const int k0 = blockIdx.x * 64;
  const int n0 = blockIdx.y * 64;
  const int t = threadIdx.x;
  {
    const int lk = t >> 2;
    const int nq = (t & 3) * 16;
    const float* src = inp + (size_t)(k0 + lk) * HID + n0 + nq;
    #pragma unroll
    for (int i = 0; i < 4; ++i) {
      float4 v = *(const float4*)(src + i * 4);
      tile[lk][nq + i * 4 + 0] = v.x;
      tile[lk][nq + i * 4 + 1] = v.y;
      tile[lk][nq + i * 4 + 2] = v.z;
      tile[lk][nq + i * 4 + 3] = v.w;
    }
  }
  __syncthreads();
  {
    const int ln = t >> 2;
    const int kq = (t & 3) * 16;
    f16* dst = outp + (size_t)(n0 + ln) * K + k0 + kq;
    f16x8 a, b;
    #pragma unroll
    for (int j = 0; j < 8; ++j) a[j] = (f16)tile[kq + j][ln];
    #pragma unroll
    for (int j = 0; j < 8; ++j) b[j] = (f16)tile[kq + 8 + j][ln];
    *(f16x8*)dst = a;
    *(f16x8*)(dst + 8) = b;
  }
}

// ---------------------------------------------------------------------------
// Fused MLP R17 = R13 chassis with HALF the L1 barriers (8 instead of 16):
//  - bS is wave-private on BOTH sides -> single 32 KB buffer, staged after
//    the wave's own lgkm-drain (no barrier ever needed for bS).
//  - aS QUAD buffer (4 x 8 KB), stage distance 2: one barrier (after odd
//    phases) publishes TWO staged A tiles. WAR: buf[c&3] rewritten at c+4,
//    last read at c, >=1 barrier between (verified both parities).
//  - Steady vmcnt: entering phase c queue = [pa(c+3)4, gll(c)8, pa(c+4)4]
//    -> VM(4) forces gll(c), keeps pa(c+4). pa: 3 sets, load distance 5
//    (realized cover ~2 phases due to in-order drain).
//  - Hidden layers: R13 VERBATIM (wS 3-buffer gll + VM(8) -- beat reg-B in
//    R16), buffers remapped to 64K/32K/48K (64K region is free at phase 15,
//    avoiding the single-bS overlap race; 32K/48K staged after bS dies).
//  - Arena 80 KB, launch_bounds(256,2): same occupancy/VGPR as R13.
// ---------------------------------------------------------------------------

__device__ __forceinline__ void zero_acc(f32x4 (&acc)[4][4]) {
  #pragma unroll
  for (int a = 0; a < 4; ++a)
    #pragma unroll
    for (int b = 0; b < 4; ++b)
      #pragma unroll
      for (int j = 0; j < 4; ++j) acc[a][b][j] = 0.f;
}

// L1 weights: bS [256 n][8 slots of 16B]; phys slot p at row r holds k-slot
// p^(r&7). Wave w stages rows w*64..+63 -- exactly the rows it alone reads.
__device__ __forceinline__ void stage_w64(char* bS, const char* wbase, int c,
                                          int w, int lane)
{
  #pragma unroll
  for (int i = 0; i < 8; ++i) {
    const int seg  = w * 8 + i;                 // 0..31
    const int rloc = lane >> 3;                 // 0..7
    const int p    = lane & 7;                  // phys 16B slot
    const int row  = seg * 8 + rloc;            // 0..255
    const int slog = p ^ rloc;                  // logical k-slot (row&7 == rloc)
    const char* gp = wbase + (size_t)row * (NF * 2) + (size_t)c * 128 + slog * 16;
    char* lp = bS + seg * 1024;                 // wave-uniform base
    __builtin_amdgcn_global_load_lds((const GLB u32*)gp, (AS3 u32*)lp, 16, 0, 0);
  }
}

// Hidden weights: [256 n][32 k], phys slot = log ^ ((row>>1)&3). Self-staged.
__device__ __forceinline__ void stage_w32(char* wS, const char* wbase, int c,
                                          int w, int lane)
{
  #pragma unroll
  for (int i = 0; i < 4; ++i) {
    const int seg = w * 4 + i;                  // 0..15
    const int row = seg * 16 + (lane >> 2);     // 0..255
    const int kbp = lane & 3;
    const int kb  = kbp ^ ((row >> 1) & 3);
    const char* gp = wbase + (size_t)row * (HID * 2) + c * 64 + kb * 16;
    char* lp = wS + seg * 1024;
    __builtin_amdgcn_global_load_lds((const GLB u32*)gp, (AS3 u32*)lp, 16, 0, 0);
  }
}

__device__ __forceinline__ void load_pa(float4 (&pa)[4], const float* fsrcT, int c)
{
  #pragma unroll
  for (int j = 0; j < 4; ++j)
    pa[j] = *(const float4*)(fsrcT + c * 64 + j * 4);
}

// Features chunk [64 r][64 k] fp32->fp16 into aS (ds_write).
__device__ __forceinline__ void stage_feat64(char* aS, const float4 (&pa)[4], int t)
{
  const int r = t >> 2;
  #pragma unroll
  for (int wr = 0; wr < 2; ++wr) {
    f16x8 hv;
    const float4 lo = pa[wr * 2 + 0], hi = pa[wr * 2 + 1];
    hv[0]=(f16)lo.x; hv[1]=(f16)lo.y; hv[2]=(f16)lo.z; hv[3]=(f16)lo.w;
    hv[4]=(f16)hi.x; hv[5]=(f16)hi.y; hv[6]=(f16)hi.z; hv[7]=(f16)hi.w;
    const int slog = (t & 3) * 2 + wr;
    const int p = slog ^ (r & 7);
    *(f16x8*)(aS + r * 128 + p * 16) = hv;
  }
}

// L1 compute: one KC=64 chunk, 32 MFMA.
__device__ __forceinline__ void mfma64_a(f32x4 (&acc)[4][4], const char* aS,
                                         const char* bS, int w, int g, int l15)
{
  #pragma unroll
  for (int ks = 0; ks < 2; ++ks) {
    f16x8 af[4], bf[4];
    #pragma unroll
    for (int at = 0; at < 4; ++at) {
      const int rr = at * 16 + l15;
      const int p  = (ks * 4 + g) ^ (rr & 7);
      af[at] = *(const f16x8*)(aS + rr * 128 + p * 16);
    }
    #pragma unroll
    for (int bt = 0; bt < 4; ++bt) {
      const int nn = w * 64 + bt * 16 + l15;
      const int p  = (ks * 4 + g) ^ (nn & 7);
      bf[bt] = *(const f16x8*)(bS + nn * 128 + p * 16);
    }
    #pragma unroll
    for (int at = 0; at < 4; ++at)
      #pragma unroll
      for (int bt = 0; bt < 4; ++bt)
        acc[at][bt] = __builtin_amdgcn_mfma_f32_16x16x32_f16(af[at], bf[bt], acc[at][bt], 0, 0, 0);
  }
}

// Hidden compute: one KC=32 chunk, 16 MFMA.
__device__ __forceinline__ void mfma32_h(f32x4 (&acc)[4][4], const char* hL, int c,
                                         const char* wS, int w, int g, int l15)
{
  f16x8 af[4], bf[4];
  #pragma unroll
  for (int at = 0; at < 4; ++at) {
    const int rr = at * 16 + l15;
    af[at] = *(const f16x8*)(hL + ((rr * 512 + c * 64 + g * 16) ^ ((rr & 7) << 4)));
  }
  #pragma unroll
  for (int bt = 0; bt < 4; ++bt) {
    const int nn = w * 64 + bt * 16 + l15;
    bf[bt] = *(const f16x8*)(wS + nn * 64 + ((g ^ ((nn >> 1) & 3)) * 16));
  }
  #pragma unroll
  for (int at = 0; at < 4; ++at)
    #pragma unroll
    for (int bt = 0; bt < 4; ++bt)
      acc[at][bt] = __builtin_amdgcn_mfma_f32_16x16x32_f16(af[at], bf[bt], acc[at][bt], 0, 0, 0);
}

__device__ __forceinline__ void silu_store(f32x4 (&acc)[4][4],
                                           const float* __restrict__ bias,
                                           char* hL, int w, int lane)
{
  const int g = lane >> 4, l15 = lane & 15;
  #pragma unroll
  for (int bt = 0; bt < 4; ++bt) {
    const int col = w * 64 + bt * 16 + l15;
    const float b = bias[col];
    #pragma unroll
    for (int at = 0; at < 4; ++at) {
      #pragma unroll
      for (int j = 0; j < 4; ++j) {
        const int row = at * 16 + g * 4 + j;   // m89-verified C/D mapping
        float x = acc[at][bt][j] + b;
        x = x * __builtin_amdgcn_rcpf(1.f + __expf(-x));
        *(f16*)(hL + (((row * HID + col) * 2) ^ ((row & 7) << 4))) = (f16)x;
      }
    }
  }
}

// aS quad-buffer select (8 KB each)
#define ASB(c) (arena + (((c) & 3) << 13))

// L1 phase c: VM forces own gll(c); compute chunk c; lgkm retires own
// ds_reads (WAR gate for the single-bS overwrite); gll W1(c+1) into own
// slice; stage feat(c+2) into quad slot; refill pa(c+5); barrier only on
// odd phases (publishes the two A tiles staged since the last barrier).
#define L1_STEP(c, PAset, VMN, DOG, DOF, DOPA, DOBAR)            \
  do {                                                           \
    WAIT_VM(VMN); SCHED0();                                      \
    mfma64_a(acc, ASB(c), bS, w, g, l15);                        \
    WAIT_LGKM(); SCHED0();                                       \
    if (DOG)  stage_w64(bS, w1s, (c) + 1, w, lane);              \
    if (DOF)  stage_feat64(ASB((c) + 2), PAset, t);              \
    if (DOPA) load_pa(PAset, fsrcT, (c) + 5);                    \
    if (DOBAR) { WAIT_LGKM(); BARRIER(); }                       \
  } while (0)

// Hidden step (R13 verbatim): counted wait readies chunk c, compute, drain
// own reads, stage chunk c+3 into the buffer just freed. Barrier-free.
#define HID_ST(c, WSc, wsrc, cs)                                 \
  do {                                                           \
    WAIT_VM(8); SCHED0();                                        \
    mfma32_h(acc, hL, c, WSc, w, g, l15);                        \
    WAIT_LGKM(); SCHED0();                                       \
    stage_w32(WSc, wsrc, cs, w, lane);                           \
  } while (0)

__global__ __launch_bounds__(256, 2) void mlp_fused_kernel(
    const float* __restrict__ feats,
    const float* __restrict__ b1g,
    const float* __restrict__ b2g,
    const float* __restrict__ b3g,
    const float* __restrict__ w4g,
    const float* __restrict__ b4g,
    const int*   __restrict__ sidxg,
    const f16*   __restrict__ w1t,
    const f16*   __restrict__ w2t,
    const f16*   __restrict__ w3t,
    float*       __restrict__ outg)
{
  __shared__ char arena[80 * 1024];
  char* bS  = arena + 32 * 1024;     // L1 weights: single 32 KB (wave-private)
  char* hL  = arena;                 // hidden: h [64][256] fp16, 32 KB overlay
  char* wH0 = arena + 64 * 1024;     // hidden weights rotation: 3 x 16 KB
  char* wH1 = arena + 32 * 1024;     //   (wH0 free at ph15; wH1/wH2 over bS)
  char* wH2 = arena + 48 * 1024;

  const int s    = blockIdx.y;
  const int row0 = blockIdx.x * TM;
  const int t    = threadIdx.x;
  const int lane = t & 63;
  const int w    = t >> 6;           // 0..3; wave w owns output cols w*64..+63
  const int g    = lane >> 4;
  const int l15  = lane & 15;

  const int gr   = row0 + (t >> 2);
  const bool valid = gr < NPER;
  const int grc  = valid ? gr : (NPER - 1);
  const float* fsrcT = feats + ((size_t)s * NPER + grc) * NF + (t & 3) * 16;
  const char*  w1s   = (const char*)(w1t + (size_t)s * HID * NF);
  const char*  w2s   = (const char*)(w2t + (size_t)s * HID * HID);
  const char*  w3s   = (const char*)(w3t + (size_t)s * HID * HID);

  f32x4 acc[4][4];
  zero_acc(acc);

  // ===== L1 prologue: aS(0),aS(1) staged; gll(0); pa(2..4) in 3 sets =====
  float4 pf0[4], pf1[4], paA[4], paB[4], paC[4];
  load_pa(pf0, fsrcT, 0);
  load_pa(pf1, fsrcT, 1);
  stage_w64(bS, w1s, 0, w, lane);
  load_pa(paA, fsrcT, 2);
  load_pa(paB, fsrcT, 3);
  load_pa(paC, fsrcT, 4);
  stage_feat64(ASB(0), pf0, t);      // compiler waits pf0 only (keeps gll/pa)
  stage_feat64(ASB(1), pf1, t);      // compiler waits pf1 only
  WAIT_LGKM(); BARRIER();            // publish aS(0), aS(1)

  // ===== L1: 16 phases, KC=64, quad aS, single bS, barrier every 2 =====
  // Set map: phase c consumes pa(c+2) from set[c%3], reloads it <- pa(c+5).
  L1_STEP(0,  paA, 12, 1, 1, 1, 0);
  L1_STEP(1,  paB,  4, 1, 1, 1, 1);
  L1_STEP(2,  paC,  4, 1, 1, 1, 0);
  L1_STEP(3,  paA,  4, 1, 1, 1, 1);
  L1_STEP(4,  paB,  4, 1, 1, 1, 0);
  L1_STEP(5,  paC,  4, 1, 1, 1, 1);
  L1_STEP(6,  paA,  4, 1, 1, 1, 0);
  L1_STEP(7,  paB,  4, 1, 1, 1, 1);
  L1_STEP(8,  paC,  4, 1, 1, 1, 0);
  L1_STEP(9,  paA,  4, 1, 1, 1, 1);
  L1_STEP(10, paB,  4, 1, 1, 1, 0);  // loads pa(15) -> paB (last pa)
  L1_STEP(11, paC,  4, 1, 1, 0, 1);  // stage aS(13)
  L1_STEP(12, paA,  0, 1, 1, 0, 0);  // stage aS(14) from pa(14)=paA
  L1_STEP(13, paB,  0, 1, 1, 0, 1);  // stage aS(15) from pa(15)=paB
  L1_STEP(14, paC,  0, 1, 0, 0, 0);  // gll(15); no more feat staging
  { // phase 15: last chunk; early-stage W2 chunk0 into wH0 (free region)
    WAIT_VM(0); SCHED0();
    mfma64_a(acc, ASB(15), bS, w, g, l15);
    WAIT_LGKM(); SCHED0();
    stage_w32(wH0, w2s, 0, w, lane);
    WAIT_LGKM(); BARRIER();          // all aS/bS reads done block-wide
  }

  // ===== L1 -> L2: h over dead aS; fill wS pipeline over dead bS =====
  silu_store(acc, b1g + s * HID, hL, w, lane);
  zero_acc(acc);
  stage_w32(wH1, w2s, 1, w, lane);
  stage_w32(wH2, w2s, 2, w, lane);
  WAIT_LGKM(); BARRIER();            // hL published

  // ===== Layer 2: 8 chunks, KC=32, barrier-free, 3-buf wS, VM(8) =====
  HID_ST(0, wH0, w2s, 3);
  HID_ST(1, wH1, w2s, 4);
  HID_ST(2, wH2, w2s, 5);
  HID_ST(3, wH0, w2s, 6);
  HID_ST(4, wH1, w2s, 7);
  HID_ST(5, wH2, w3s, 0);            // cross into W3 prefetch
  HID_ST(6, wH0, w3s, 1);
  HID_ST(7, wH1, w3s, 2);
  BARRIER();                         // all waves done reading hL
  silu_store(acc, b2g + s * HID, hL, w, lane);
  zero_acc(acc);
  WAIT_LGKM(); BARRIER();            // hL published

  // ===== Layer 3: 8 chunks; in flight: 0(wH2),1(wH0),2(wH1) =====
  HID_ST(0, wH2, w3s, 3);
  HID_ST(1, wH0, w3s, 4);
  HID_ST(2, wH1, w3s, 5);
  HID_ST(3, wH2, w3s, 6);
  HID_ST(4, wH0, w3s, 7);
  { WAIT_VM(8); SCHED0(); mfma32_h(acc, hL, 5, wH1, w, g, l15); }
  { WAIT_VM(4); SCHED0(); mfma32_h(acc, hL, 6, wH2, w, g, l15); }
  { WAIT_VM(0); SCHED0(); mfma32_h(acc, hL, 7, wH0, w, g, l15); }
  BARRIER();
  silu_store(acc, b3g + s * HID, hL, w, lane);
  WAIT_LGKM(); BARRIER();

  // ===== Layer 4: e = h @ W4 + b4; segment-sum via atomicAdd =====
  {
    const int row = t >> 2;
    const int q   = t & 3;
    const float* w4 = w4g + s * HID;
    float sum = 0.f;
    #pragma unroll
    for (int j8 = 0; j8 < 64; j8 += 8) {
      const int k = q * 64 + j8;
      f16x8 hv = *(const f16x8*)(hL + (((row * HID + k) * 2) ^ ((row & 7) << 4)));
      float4 wa = *(const float4*)(w4 + k);
      float4 wb = *(const float4*)(w4 + k + 4);
      sum += (float)hv[0] * wa.x + (float)hv[1] * wa.y + (float)hv[2] * wa.z + (float)hv[3] * wa.w
           + (float)hv[4] * wb.x + (float)hv[5] * wb.y + (float)hv[6] * wb.z + (float)hv[7] * wb.w;
    }
    sum += __shfl_xor(sum, 1);
    sum += __shfl_xor(sum, 2);
    if (q == 0 && valid) {
      atomicAdd(&outg[sidxg[s * NPER + gr]], sum + b4g[s]);
    }
  }
}

// ---------------------------------------------------------------------------
extern "C" void kernel_launch(void* const* d_in, const int* in_sizes, int n_in,
                              void* d_out, int out_size, void* d_ws, size_t ws_size,
                              hipStream_t stream)
{
  const float* feats = (const float*)d_in[0];
  const float* W1    = (const float*)d_in[1];
  const float* b1    = (const float*)d_in[2];
  const float* W2    = (const float*)d_in[3];
  const float* b2    = (const float*)d_in[4];
  const float* W3    = (const float*)d_in[5];
  const float* b3    = (const float*)d_in[6];
  const float* W4    = (const float*)d_in[7];
  const float* b4    = (const float*)d_in[8];
  const int*   sidx  = (const int*)d_in[9];
  float* out = (float*)d_out;

  f16* w1t = (f16*)d_ws;                              // [S][256][1024] fp16
  f16* w2t = w1t + (size_t)S_ * HID * NF;             // [S][256][256]  fp16
  f16* w3t = w2t + (size_t)S_ * HID * HID;            // [S][256][256]  fp16

  hipMemsetAsync(d_out, 0, NSTRUCT * sizeof(float), stream);
  transpose_all_kernel<<<dim3(16, 4, 12), 256, 0, stream>>>(W1, W2, W3, w1t, w2t, w3t);
  mlp_fused_kernel<<<dim3((NPER + TM - 1) / TM, S_), 256, 0, stream>>>(
      feats, b1, b2, b3, W4, b4, sidx, w1t, w2t, w3t, out);
}